// Round 6
// baseline (126.214 us; speedup 1.0000x reference)
//
#include <hip/hip_runtime.h>
#include <hip/hip_bf16.h>

typedef __attribute__((ext_vector_type(8))) short short8;
typedef __attribute__((ext_vector_type(4))) short short4v;  // 8 B
typedef __attribute__((ext_vector_type(4))) float f32x4;

#define LDST 72   // bf16 elems per LDS A row (64 + 8 pad); 144 B = 9x16B (odd) -> conflict-free
#define NCH 4     // row-chunks per block

static __device__ __forceinline__ unsigned short f2bf(float f) {
    union { __hip_bfloat16 h; unsigned short u; } cv;
    cv.h = __float2bfloat16(f);
    return cv.u;
}

// Build Wbig[m=o*8+k][kk=f*8+j] = sum_i C[i,j,k] * W[i,o,f], cast to bf16.
__global__ __launch_bounds__(256) void build_wbig(const float* __restrict__ W,
                                                  unsigned short* __restrict__ Wbig) {
    __shared__ float C[8][8][8];
    const int t = threadIdx.x;
    for (int i = t; i < 512; i += 256) ((float*)C)[i] = 0.0f;
    __syncthreads();
    if (t == 0) {
        C[0][0][0] = 1.0f;
        for (int i = 1; i < 8; ++i) { C[0][i][i] = 1.0f; C[i][0][i] = 1.0f; C[i][i][0] = -1.0f; }
        const int tr[7][3] = {{1,2,3},{1,4,5},{1,7,6},{2,4,6},{2,5,7},{3,4,7},{3,6,5}};
        for (int q = 0; q < 7; ++q) {
            const int a = tr[q][0], b = tr[q][1], c = tr[q][2];
            const int p[3][3] = {{a,b,c},{b,c,a},{c,a,b}};
            for (int u = 0; u < 3; ++u) {
                C[p[u][0]][p[u][1]][p[u][2]] = 1.0f;
                C[p[u][1]][p[u][0]][p[u][2]] = -1.0f;
            }
        }
    }
    __syncthreads();
    const int e = blockIdx.x * 256 + t;     // 0..262143
    const int m = e >> 9, kk = e & 511;
    const int o = m >> 3, k = m & 7, f = kk >> 3, j = kk & 7;
    float s = 0.0f;
#pragma unroll
    for (int i = 0; i < 8; ++i) s += C[i][j][k] * W[i * 4096 + o * 64 + f];
    Wbig[e] = f2bf(s);
}

// Out[65536][512] = X(fp32->bf16) * Wbig^T + bias.
// 16 waves/block; each wave owns 32 output cols with B entirely in registers.
// A: 64x64 tile double-buffered in LDS. Raw barrier (lgkmcnt only) keeps the
// depth-3 global prefetch in flight across iterations (no vmcnt(0) drain).
__global__ __launch_bounds__(1024, 4) void oct_gemm(const float* __restrict__ X,
                                                    const unsigned short* __restrict__ Wbig,
                                                    const float* __restrict__ Bias,
                                                    float* __restrict__ Out) {
    __shared__ unsigned short As[2][64 * LDST];   // 2 x 9 KB

    const int t    = threadIdx.x;       // 0..1023
    const int lane = t & 63;
    const int w    = t >> 6;            // wave 0..15 -> cols [w*32, w*32+32)
    const int l15  = lane & 15;
    const int l4   = lane >> 4;         // 0..3

    // ---- B in registers: breg[ni][ks] covers col = w*32+ni*16+l15, k = ks*32+l4*8+0..7
    short8 breg[2][16];
    {
        const unsigned short* bp = Wbig + (size_t)(w * 32 + l15) * 512 + l4 * 8;
#pragma unroll
        for (int ni = 0; ni < 2; ++ni)
#pragma unroll
            for (int ks = 0; ks < 16; ++ks)
                breg[ni][ks] = *reinterpret_cast<const short8*>(bp + (size_t)ni * 16 * 512 + ks * 32);
    }

    const float bv0 = Bias[w * 32 + l15];
    const float bv1 = Bias[w * 32 + 16 + l15];

    // A staging coords: 16 threads per row, 4 fp32 each (256 B contiguous per row).
    const int srow  = t >> 4;           // 0..63
    const int scol4 = (t & 15) * 4;     // fp32 col 0..60

    for (int ch = 0; ch < NCH; ++ch) {
        const int rowBase = ((ch << 8) + (int)blockIdx.x) << 6;   // (ch*256+bid)*64
        const float* Xp = X + (size_t)(rowBase + srow) * 512 + scol4;

        f32x4 va[3];

#define LD(SLOT, KT) va[SLOT] = *reinterpret_cast<const f32x4*>(Xp + (KT))
#define WRITE(BUF, SLOT) do { \
        short4v p; \
        p[0] = (short)f2bf(va[SLOT][0]); p[1] = (short)f2bf(va[SLOT][1]); \
        p[2] = (short)f2bf(va[SLOT][2]); p[3] = (short)f2bf(va[SLOT][3]); \
        *reinterpret_cast<short4v*>(&As[BUF][srow * LDST + scol4]) = p; \
    } while (0)
#define BARRIER() do { \
        asm volatile("s_waitcnt lgkmcnt(0)" ::: "memory"); \
        __builtin_amdgcn_s_barrier(); \
    } while (0)

        // acc init = bias (D col = lane&15 for all 4 regs)
        f32x4 acc[4][2];
#pragma unroll
        for (int mi = 0; mi < 4; ++mi) {
            acc[mi][0] = (f32x4){bv0, bv0, bv0, bv0};
            acc[mi][1] = (f32x4){bv1, bv1, bv1, bv1};
        }

        // prologue: 3 tiles in flight
        LD(0, 0); LD(1, 64); LD(2, 128);
        WRITE(0, 0);                    // counted vmcnt: waits only va[0]
        BARRIER();

#pragma unroll
        for (int it = 0; it < 8; ++it) {
            if (it <= 4) LD(it % 3, (it + 3) * 64);    // prefetch depth 3

            // MFMA phase: LDS A + register B only
#pragma unroll
            for (int kk = 0; kk < 2; ++kk) {
                const int kb = kk * 32 + l4 * 8;
                short8 a[4];
#pragma unroll
                for (int mi = 0; mi < 4; ++mi)
                    a[mi] = *reinterpret_cast<const short8*>(
                        &As[it & 1][(mi * 16 + l15) * LDST + kb]);
#pragma unroll
                for (int mi = 0; mi < 4; ++mi) {
                    acc[mi][0] = __builtin_amdgcn_mfma_f32_16x16x32_bf16(
                        a[mi], breg[0][it * 2 + kk], acc[mi][0], 0, 0, 0);
                    acc[mi][1] = __builtin_amdgcn_mfma_f32_16x16x32_bf16(
                        a[mi], breg[1][it * 2 + kk], acc[mi][1], 0, 0, 0);
                }
            }

            if (it < 7) WRITE((it + 1) & 1, (it + 1) % 3);  // counted vmcnt (2 newer in flight)
            BARRIER();
        }

        // epilogue: fp32 stores (same verified pattern as R1/R4: 131 MB clean)
#pragma unroll
        for (int mi = 0; mi < 4; ++mi) {
            const int row0 = rowBase + mi * 16 + l4 * 4;
#pragma unroll
            for (int ni = 0; ni < 2; ++ni) {
                const int col = w * 32 + ni * 16 + l15;
#pragma unroll
                for (int r = 0; r < 4; ++r)
                    Out[(size_t)(row0 + r) * 512 + col] = acc[mi][ni][r];
            }
        }
#undef LD
#undef WRITE
#undef BARRIER
    }
}

extern "C" void kernel_launch(void* const* d_in, const int* in_sizes, int n_in,
                              void* d_out, int out_size, void* d_ws, size_t ws_size,
                              hipStream_t stream) {
    const float* x = (const float*)d_in[0];   // [65536][512]
    const float* W = (const float*)d_in[1];   // [8][64][64]
    const float* b = (const float*)d_in[2];   // [512]
    float* out = (float*)d_out;               // [65536][512]
    unsigned short* Wbig = (unsigned short*)d_ws;  // 512*512 bf16 = 512 KB

    build_wbig<<<1024, 256, 0, stream>>>(W, Wbig);
    oct_gemm<<<256, 1024, 0, stream>>>(x, Wbig, b, out);
}

// Round 7
// 89.856 us; speedup vs baseline: 1.4046x; 1.4046x over previous
//
#include <hip/hip_runtime.h>
#include <hip/hip_bf16.h>

typedef __attribute__((ext_vector_type(8))) short short8;
typedef __attribute__((ext_vector_type(4))) short short4v;  // 8 B
typedef __attribute__((ext_vector_type(4))) float f32x4;

#define LDST 72   // bf16 elems per LDS A row (64 + 8 pad)

static __device__ __forceinline__ unsigned short f2bf(float f) {
    union { __hip_bfloat16 h; unsigned short u; } cv;
    cv.h = __float2bfloat16(f);
    return cv.u;
}

// Build Wbig[m=o*8+k][kk=f*8+j] = sum_i C[i,j,k] * W[i,o,f], cast to bf16.
__global__ __launch_bounds__(256) void build_wbig(const float* __restrict__ W,
                                                  unsigned short* __restrict__ Wbig) {
    __shared__ float C[8][8][8];
    const int t = threadIdx.x;
    for (int i = t; i < 512; i += 256) ((float*)C)[i] = 0.0f;
    __syncthreads();
    if (t == 0) {
        C[0][0][0] = 1.0f;
        for (int i = 1; i < 8; ++i) { C[0][i][i] = 1.0f; C[i][0][i] = 1.0f; C[i][i][0] = -1.0f; }
        const int tr[7][3] = {{1,2,3},{1,4,5},{1,7,6},{2,4,6},{2,5,7},{3,4,7},{3,6,5}};
        for (int q = 0; q < 7; ++q) {
            const int a = tr[q][0], b = tr[q][1], c = tr[q][2];
            const int p[3][3] = {{a,b,c},{b,c,a},{c,a,b}};
            for (int u = 0; u < 3; ++u) {
                C[p[u][0]][p[u][1]][p[u][2]] = 1.0f;
                C[p[u][1]][p[u][0]][p[u][2]] = -1.0f;
            }
        }
    }
    __syncthreads();
    const int e = blockIdx.x * 256 + t;     // 0..262143
    const int m = e >> 9, kk = e & 511;
    const int o = m >> 3, k = m & 7, f = kk >> 3, j = kk & 7;
    float s = 0.0f;
#pragma unroll
    for (int i = 0; i < 8; ++i) s += C[i][j][k] * W[i * 4096 + o * 64 + f];
    Wbig[e] = f2bf(s);
}

// Out[65536][512] = X(fp32->bf16) * Wbig^T + bias.
// 1024 threads = 16 waves; each wave owns 16 output cols, B slice in 64 VGPR.
// A: 64x64 tile double-buffered in LDS, staged via reg (fp32->bf16 cvt).
// Flattened 8-chunk x 8-kstep pipeline, depth-4 reg prefetch, counted vmcnt,
// raw s_barrier + lgkmcnt(0) only (global loads never drained).
__global__ __launch_bounds__(1024) void oct_gemm(const float* __restrict__ X,
                                                 const unsigned short* __restrict__ Wbig,
                                                 const float* __restrict__ Bias,
                                                 float* __restrict__ Out) {
    __shared__ unsigned short As[2][64 * LDST];   // 2 x 9 KB

    const int t    = threadIdx.x;       // 0..1023
    const int lane = t & 63;
    const int w    = t >> 6;            // wave 0..15
    const int l15  = lane & 15;
    const int l4   = lane >> 4;         // 0..3

    // XCD pairing: partner blocks (colHalf 0/1 of same stripe-group) -> same XCD.
    const int p  = blockIdx.x;                  // 0..255
    const int L  = (p & 7) * 32 + (p >> 3);     // 32 consecutive L per XCD
    const int colHalf = L & 1;
    const int sg = L >> 1;                      // 0..127; stripes [sg*8, sg*8+8)

    const int col = colHalf * 256 + w * 16 + l15;   // this lane's output col

    // B in registers: breg[ks] covers col, k = ks*32 + l4*8 + 0..7  (64 VGPR)
    short8 breg[16];
    {
        const unsigned short* bp = Wbig + (size_t)col * 512 + l4 * 8;
#pragma unroll
        for (int ks = 0; ks < 16; ++ks)
            breg[ks] = *reinterpret_cast<const short8*>(bp + ks * 32);
    }
    const float bv = Bias[col];

    // A staging coords: 16 threads/row, one f32x4 each
    const int srow = t >> 4;            // 0..63
    const int sc4  = (t & 15) * 4;      // fp32 col 0..60

    f32x4 va[4];                        // depth-4 in-flight tiles (16 VGPR)
    f32x4 acc[4];                       // 4 m-frags x 1 n-frag (16 VGPR)
#pragma unroll
    for (int mi = 0; mi < 4; ++mi) acc[mi] = (f32x4){bv, bv, bv, bv};

    // ---- prologue: tiles 0..3 of chunk 0 in flight; write tile 0 (vmcnt counted)
    {
        const int rowBase0 = sg * 8 * 64;
        const float* xb = X + (size_t)(rowBase0 + srow) * 512 + sc4;
#pragma unroll
        for (int s = 0; s < 4; ++s)
            va[s] = *reinterpret_cast<const f32x4*>(xb + s * 64);
        short4v pk;
        pk[0] = (short)f2bf(va[0][0]); pk[1] = (short)f2bf(va[0][1]);
        pk[2] = (short)f2bf(va[0][2]); pk[3] = (short)f2bf(va[0][3]);
        *reinterpret_cast<short4v*>(&As[0][srow * LDST + sc4]) = pk;
        asm volatile("s_waitcnt lgkmcnt(0)" ::: "memory");
        __builtin_amdgcn_s_barrier();
        asm volatile("" ::: "memory");
    }

    for (int item = 0; item < 8; ++item) {
        const int rowBase = (sg * 8 + item) * 64;
#pragma unroll
        for (int it = 0; it < 8; ++it) {
            // ---- prefetch tile g+4 into slot (it+4)&3 == it&3 (static)
            if (it < 4) {
                const float* src = X + (size_t)(rowBase + srow) * 512 + (it + 4) * 64 + sc4;
                va[it & 3] = *reinterpret_cast<const f32x4*>(src);
            } else if (item < 7) {
                const float* src = X + (size_t)(rowBase + 64 + srow) * 512 + (it - 4) * 64 + sc4;
                va[it & 3] = *reinterpret_cast<const f32x4*>(src);
            }

            // ---- MFMA phase on buf it&1 (LDS A + register B only)
#pragma unroll
            for (int kk = 0; kk < 2; ++kk) {
#pragma unroll
                for (int mi = 0; mi < 4; ++mi) {
                    const short8 a = *reinterpret_cast<const short8*>(
                        &As[it & 1][(mi * 16 + l15) * LDST + kk * 32 + l4 * 8]);
                    acc[mi] = __builtin_amdgcn_mfma_f32_16x16x32_bf16(
                        a, breg[it * 2 + kk], acc[mi], 0, 0, 0);
                }
            }

            // ---- write tile g+1 (slot (it+1)&3) into buf (it+1)&1; vmcnt(3) counted
            if (!(item == 7 && it == 7)) {
                const int s = (it + 1) & 3;
                short4v pk;
                pk[0] = (short)f2bf(va[s][0]); pk[1] = (short)f2bf(va[s][1]);
                pk[2] = (short)f2bf(va[s][2]); pk[3] = (short)f2bf(va[s][3]);
                *reinterpret_cast<short4v*>(&As[(it + 1) & 1][srow * LDST + sc4]) = pk;
            }

            // ---- per-chunk epilogue: store acc, reinit (overlaps via vmcnt slack)
            if (it == 7) {
#pragma unroll
                for (int mi = 0; mi < 4; ++mi) {
#pragma unroll
                    for (int r = 0; r < 4; ++r)
                        Out[(size_t)(rowBase + mi * 16 + l4 * 4 + r) * 512 + col] = acc[mi][r];
                    acc[mi] = (f32x4){bv, bv, bv, bv};
                }
            }

            asm volatile("s_waitcnt lgkmcnt(0)" ::: "memory");
            __builtin_amdgcn_s_barrier();
            asm volatile("" ::: "memory");
        }
    }
}

extern "C" void kernel_launch(void* const* d_in, const int* in_sizes, int n_in,
                              void* d_out, int out_size, void* d_ws, size_t ws_size,
                              hipStream_t stream) {
    const float* x = (const float*)d_in[0];   // [65536][512]
    const float* W = (const float*)d_in[1];   // [8][64][64]
    const float* b = (const float*)d_in[2];   // [512]
    float* out = (float*)d_out;               // [65536][512]
    unsigned short* Wbig = (unsigned short*)d_ws;  // 512*512 bf16 = 512 KB

    build_wbig<<<1024, 256, 0, stream>>>(W, Wbig);
    oct_gemm<<<256, 1024, 0, stream>>>(x, Wbig, b, out);
}

// Round 8
// 67.058 us; speedup vs baseline: 1.8822x; 1.3400x over previous
//
#include <hip/hip_runtime.h>
#include <hip/hip_bf16.h>

typedef __attribute__((ext_vector_type(8))) short short8;
typedef __attribute__((ext_vector_type(4))) float f32x4;

#define BM 256
#define BN 256
#define BK 64
#define LDST 72   // bf16 elems per LDS row (64 + 8 pad): 144 B rows -> ~2-way (free) on b128
#define NKT 8     // 512 / BK
#define TILE_ELEMS (256 * LDST)

static __device__ __forceinline__ unsigned short f2bf(float f) {
    union { __hip_bfloat16 h; unsigned short u; } cv;
    cv.h = __float2bfloat16(f);
    return cv.u;
}

// Build Wbig[m=o*8+k][kk=f*8+j] = sum_i C[i,j,k] * W[i,o,f], cast to bf16.
__global__ __launch_bounds__(256) void build_wbig(const float* __restrict__ W,
                                                  unsigned short* __restrict__ Wbig) {
    __shared__ float C[8][8][8];
    const int t = threadIdx.x;
    for (int i = t; i < 512; i += 256) ((float*)C)[i] = 0.0f;
    __syncthreads();
    if (t == 0) {
        C[0][0][0] = 1.0f;
        for (int i = 1; i < 8; ++i) { C[0][i][i] = 1.0f; C[i][0][i] = 1.0f; C[i][i][0] = -1.0f; }
        const int tr[7][3] = {{1,2,3},{1,4,5},{1,7,6},{2,4,6},{2,5,7},{3,4,7},{3,6,5}};
        for (int q = 0; q < 7; ++q) {
            const int a = tr[q][0], b = tr[q][1], c = tr[q][2];
            const int p[3][3] = {{a,b,c},{b,c,a},{c,a,b}};
            for (int u = 0; u < 3; ++u) {
                C[p[u][0]][p[u][1]][p[u][2]] = 1.0f;
                C[p[u][1]][p[u][0]][p[u][2]] = -1.0f;
            }
        }
    }
    __syncthreads();
    const int e = blockIdx.x * 256 + t;     // 0..262143
    const int m = e >> 9, kk = e & 511;
    const int o = m >> 3, k = m & 7, f = kk >> 3, j = kk & 7;
    float s = 0.0f;
#pragma unroll
    for (int i = 0; i < 8; ++i) s += C[i][j][k] * W[i * 4096 + o * 64 + f];
    Wbig[e] = f2bf(s);
}

// Out[65536][512] = X(fp32->bf16) * Wbig^T + bias.
// 256x256 tile, 8 waves (2Mx4N, wave-tile 128x64 -> low LDS frag traffic),
// A+B double-buffered in LDS. No-drain schedule: issue loads(t+1) -> MFMA
// (LDS-only) -> cvt+ds_write(t+1) (vmcnt auto-counted, covered by MFMA phase)
// -> lgkmcnt(0) + raw s_barrier. One barrier per K-iter; vmcnt never drained.
__global__ __launch_bounds__(512, 2) void oct_gemm(const float* __restrict__ X,
                                                   const unsigned short* __restrict__ Wbig,
                                                   const float* __restrict__ Bias,
                                                   float* __restrict__ Out) {
    extern __shared__ unsigned short smem[];   // 4 * 256*72 * 2B = 144 KB
    unsigned short* As[2] = { smem,                  smem + TILE_ELEMS };
    unsigned short* Bs[2] = { smem + 2 * TILE_ELEMS, smem + 3 * TILE_ELEMS };

    // XCD swizzle: both col-tiles of a row-stripe on the same XCD (A shared in L2).
    const int bid   = blockIdx.x;        // 0..511
    const int xcd   = bid & 7;
    const int ix    = bid >> 3;          // 0..63
    const int mtile = xcd * 32 + (ix >> 1);
    const int ntile = ix & 1;
    const int rowBase = mtile * BM;
    const int colBase = ntile * BN;

    const int t    = threadIdx.x;        // 0..511
    const int lane = t & 63;
    const int wave = t >> 6;             // 0..7
    const int wr   = wave >> 2;          // 0..1  (128-row half)
    const int wc   = wave & 3;           // 0..3  (64-col quarter)
    const int l15  = lane & 15;
    const int l4   = lane >> 4;

    const int srow = t >> 3;             // 0..63 (4 row-blocks of 64)
    const int scol = (t & 7) * 8;        // 0..56

    const float*          Xrow = X    + (size_t)(rowBase + srow) * 512 + scol;
    const unsigned short* Brow = Wbig + (size_t)(colBase + srow) * 512 + scol;

    f32x4  va[8];   // in-flight A: 4 row-blocks x 8 fp32 (32 VGPR)
    short8 vb[4];   // in-flight B: 4 row-blocks x 8 bf16 (16 VGPR)

#define ISSUE_AB(KT) do { _Pragma("unroll") \
    for (int l = 0; l < 4; ++l) { \
        const float* src = Xrow + (size_t)(l * 64) * 512 + (KT); \
        va[2*l]   = *reinterpret_cast<const f32x4*>(src); \
        va[2*l+1] = *reinterpret_cast<const f32x4*>(src + 4); \
    } \
    _Pragma("unroll") \
    for (int l = 0; l < 4; ++l) \
        vb[l] = *reinterpret_cast<const short8*>(Brow + (size_t)(l * 64) * 512 + (KT)); \
    } while (0)

#define WRITE_AB(BUF) do { _Pragma("unroll") \
    for (int l = 0; l < 4; ++l) { \
        short8 p; \
        p[0]=(short)f2bf(va[2*l][0]);   p[1]=(short)f2bf(va[2*l][1]); \
        p[2]=(short)f2bf(va[2*l][2]);   p[3]=(short)f2bf(va[2*l][3]); \
        p[4]=(short)f2bf(va[2*l+1][0]); p[5]=(short)f2bf(va[2*l+1][1]); \
        p[6]=(short)f2bf(va[2*l+1][2]); p[7]=(short)f2bf(va[2*l+1][3]); \
        *reinterpret_cast<short8*>(&As[BUF][(l*64 + srow) * LDST + scol]) = p; \
    } \
    _Pragma("unroll") \
    for (int l = 0; l < 4; ++l) \
        *reinterpret_cast<short8*>(&Bs[BUF][(l*64 + srow) * LDST + scol]) = vb[l]; \
    } while (0)

    // Bias folded into accumulator init (D col = lane&15 for all 4 regs).
    f32x4 acc[8][4];
#pragma unroll
    for (int ni = 0; ni < 4; ++ni) {
        const float bv = Bias[colBase + wc * 64 + ni * 16 + l15];
#pragma unroll
        for (int mi = 0; mi < 8; ++mi) acc[mi][ni] = (f32x4){bv, bv, bv, bv};
    }

    // Prologue: tile 0 -> LDS (one-time vmcnt stall), then barrier.
    ISSUE_AB(0);
    WRITE_AB(0);
    asm volatile("s_waitcnt lgkmcnt(0)" ::: "memory");
    __builtin_amdgcn_s_barrier();

#pragma unroll
    for (int kt = 0; kt < NKT; ++kt) {
        // (B) issue next tile's global loads -> regs (in flight across MFMA phase)
        if (kt + 1 < NKT) ISSUE_AB((kt + 1) * BK);
        __builtin_amdgcn_sched_barrier(0);

        // (D) MFMA phase: LDS-only operands (compiler emits counted lgkmcnt)
#pragma unroll
        for (int kk = 0; kk < 2; ++kk) {
            const int kb = kk * 32 + l4 * 8;
            short8 b[4];
#pragma unroll
            for (int ni = 0; ni < 4; ++ni)
                b[ni] = *reinterpret_cast<const short8*>(
                    &Bs[kt & 1][(wc * 64 + ni * 16 + l15) * LDST + kb]);
            __builtin_amdgcn_s_setprio(1);
#pragma unroll
            for (int mi = 0; mi < 8; ++mi) {
                const short8 a = *reinterpret_cast<const short8*>(
                    &As[kt & 1][(wr * 128 + mi * 16 + l15) * LDST + kb]);
#pragma unroll
                for (int ni = 0; ni < 4; ++ni)
                    acc[mi][ni] = __builtin_amdgcn_mfma_f32_16x16x32_bf16(
                        a, b[ni], acc[mi][ni], 0, 0, 0);
            }
            __builtin_amdgcn_s_setprio(0);
        }
        __builtin_amdgcn_sched_barrier(0);

        // (A) cvt + stage tile t+1 (auto-counted vmcnt waits only these loads)
        if (kt + 1 < NKT) WRITE_AB((kt + 1) & 1);

        // (E) writes visible to all waves; global queue untouched
        asm volatile("s_waitcnt lgkmcnt(0)" ::: "memory");
        __builtin_amdgcn_s_barrier();
    }

    // Epilogue: plain fp32 stores (verified clean 131 MB write pattern).
#pragma unroll
    for (int mi = 0; mi < 8; ++mi) {
        const int row0 = rowBase + wr * 128 + mi * 16 + l4 * 4;
#pragma unroll
        for (int ni = 0; ni < 4; ++ni) {
            const int col = colBase + wc * 64 + ni * 16 + l15;
#pragma unroll
            for (int r = 0; r < 4; ++r)
                Out[(size_t)(row0 + r) * 512 + col] = acc[mi][ni][r];
        }
    }
#undef ISSUE_AB
#undef WRITE_AB
}

extern "C" void kernel_launch(void* const* d_in, const int* in_sizes, int n_in,
                              void* d_out, int out_size, void* d_ws, size_t ws_size,
                              hipStream_t stream) {
    const float* x = (const float*)d_in[0];   // [65536][512]
    const float* W = (const float*)d_in[1];   // [8][64][64]
    const float* b = (const float*)d_in[2];   // [512]
    float* out = (float*)d_out;               // [65536][512]
    unsigned short* Wbig = (unsigned short*)d_ws;  // 512*512 bf16 = 512 KB

    static bool attr_done = false;
    if (!attr_done) {
        hipFuncSetAttribute((const void*)oct_gemm,
                            hipFuncAttributeMaxDynamicSharedMemorySize,
                            4 * TILE_ELEMS * (int)sizeof(unsigned short));
        attr_done = true;
    }

    build_wbig<<<1024, 256, 0, stream>>>(W, Wbig);
    oct_gemm<<<512, 512, 4 * TILE_ELEMS * sizeof(unsigned short), stream>>>(x, Wbig, b, out);
}